// Round 6
// baseline (2904.673 us; speedup 1.0000x reference)
//
#include <hip/hip_runtime.h>
#include <hip/hip_bf16.h>
#include <math.h>

// Problem constants
#define Bb 16
#define Nn 64
#define Dd 4
#define Tt 40
#define Ll 10
#define Hh 128
#define Kk 4
#define Ee (Nn*(Nn-1))   // 4032
#define BNH (Bb*Nn*Hh)   // 131072

typedef __attribute__((ext_vector_type(8))) short short8;
typedef __attribute__((ext_vector_type(4))) float f32x4;

#define AS1 __attribute__((address_space(1)))
#define AS3 __attribute__((address_space(3)))

// tanh from PRE-DOUBLED argument: tanh2(2x) = tanh(x) = 1 - 2/(exp(2x)+1)
__device__ __forceinline__ float tanh2(float x2){
    float e = __expf(x2);
    float r = __builtin_amdgcn_rcpf(e + 1.0f);
    return fmaf(-2.0f, r, 1.0f);
}
__device__ __forceinline__ float tanh_fast(float x){
    return tanh2(2.0f * x);
}
__device__ __forceinline__ float sigmoid_fast(float x){
    return __builtin_amdgcn_rcpf(1.0f + __expf(-x));
}
__device__ __forceinline__ unsigned short f2bf(float x){   // RNE f32->bf16
    unsigned int u = __float_as_uint(x);
    return (unsigned short)((u + 0x7FFFu + ((u >> 16) & 1u)) >> 16);
}
// packed RNE f32x2 -> bf16x2 (v_cvt_pk_bf16_f32)
__device__ __forceinline__ unsigned int pack_bf2(float lo, float hi){
    union { __hip_bfloat162 h; unsigned int u; } cv;
    cv.h = __float22bfloat162_rn(make_float2(lo, hi));
    return cv.u;
}
// async global->LDS, 16B per lane
__device__ __forceinline__ void g2lds16(const void* g, void* l){
    __builtin_amdgcn_global_load_lds((const AS1 unsigned int*)g,
                                     (AS3 unsigned int*)l, 16, 0, 0);
}

// ---------------------------------------------------------------------------
// Precompute: W2 -> bf16 B-fragment layout (blocks 0..31); b2x2 = 2*b2 (blk 32)
// frag(k,kc,nt)[lane][i] = W2[k][kc*32+(lane>>4)*8+i][nt*16+(lane&15)]
// ---------------------------------------------------------------------------
__global__ void __launch_bounds__(256) kW2f(const float* __restrict__ W2,
                                            const float* __restrict__ b2,
                                            unsigned short* __restrict__ W2f,
                                            float* __restrict__ b2x2){
    if (blockIdx.x == 32){
        int i = threadIdx.x;
        b2x2[i]       = 2.0f * b2[i];
        b2x2[i + 256] = 2.0f * b2[i + 256];
        return;
    }
    int t    = blockIdx.x * 256 + threadIdx.x;   // 0..8191
    int lane = t & 63;
    int nt   = (t >> 6) & 7;
    int kc   = (t >> 9) & 3;
    int k    = (t >> 11) & 3;
    int col  = nt * 16 + (lane & 15);
    int fb   = kc * 32 + (lane >> 4) * 8;
    unsigned int w[4];
#pragma unroll
    for (int p = 0; p < 4; ++p){
        unsigned short lo = f2bf(W2[(k*Hh + fb + 2*p    )*Hh + col]);
        unsigned short hi = f2bf(W2[(k*Hh + fb + 2*p + 1)*Hh + col]);
        w[p] = (unsigned int)lo | ((unsigned int)hi << 16);
    }
    ((uint4*)W2f)[t] = make_uint4(w[0], w[1], w[2], w[3]);
}

// ---------------------------------------------------------------------------
// kInit: hidden==0 step-0 state: Sf = 0, Rr = 2*b1 broadcast.
// ---------------------------------------------------------------------------
__global__ void __launch_bounds__(256) kInit(const float* __restrict__ b1,
                                             float* __restrict__ Sf,
                                             float* __restrict__ Rr){
    int i = blockIdx.x*256 + threadIdx.x;   // 0..524287
    Sf[i] = 0.0f;
    Rr[i] = 2.0f * b1[((i >> 13) & 3)*Hh + (i & 127)];   // [b][k][node][h]
}

// ---------------------------------------------------------------------------
// Kernel B (MFMA, n-pair, B-frag register reuse): block = (b, npair, k).
// 2048 blocks, 256 threads.  Wave = edge-strip [16w,16w+16).
//   - per lane: A-fragments for BOTH receivers in registers (pre-doubled SR)
//   - W2f k-slice (32KB) staged once via async global_load_lds
//   - MFMA loop: each B ds_read feeds 2 MFMAs (n0, n1)
//   - epilogue per n: tanh+rel, 2x shfl, cross-wave redu, store aggp[k]
// ---------------------------------------------------------------------------
__global__ void __launch_bounds__(256) kB(const float* __restrict__ Sf,
                                          const float* __restrict__ Rr,
                                          const unsigned short* __restrict__ W2f,
                                          const float* __restrict__ b2x2,
                                          const float* __restrict__ rel,
                                          const int*   __restrict__ send_idx,
                                          float* __restrict__ aggp){
    __shared__ unsigned short w2s[32*512];   // 32KB
    __shared__ float rel_s[2][64];
    __shared__ float redu[4][2][Hh];         // 4KB

    const int blk  = blockIdx.x;
    const int k    = blk & 3;
    const int np   = (blk >> 2) & 31;
    const int b    = blk >> 7;
    const int n0   = np * 2;
    const int tid  = threadIdx.x;
    const int wave = tid >> 6;
    const int lane = tid & 63;

    // ---- async stage W2f k-slice ----
    {
        const uint4* src = (const uint4*)(W2f + (size_t)k*16384);
        uint4* dst = (uint4*)w2s;
#pragma unroll
        for (int i = 0; i < 8; ++i)
            g2lds16(src + tid + i*256, dst + tid + i*256);
    }
    if (tid < 63)                      rel_s[0][tid]     = rel[(b*Ee + n0*63 + tid)*Kk + k];
    else if (tid == 63)                rel_s[0][63]      = 0.0f;
    else if (tid >= 128 && tid < 191)  rel_s[1][tid-128] = rel[(b*Ee + (n0+1)*63 + (tid-128))*Kk + k];
    else if (tid == 191)               rel_s[1][63]      = 0.0f;

    // ---- build A-fragments for both receivers (registers only) ----
    // lane: edge e = wave*16 + (lane&15), f-octet fo = lane>>4
    const int e  = wave*16 + (lane & 15);
    const int fo = lane >> 4;
    const float* SfB = Sf + (size_t)((b*4 + k)*16)*512;
    short8 a0[4], a1[4];
#pragma unroll
    for (int n = 0; n < 2; ++n){
        const int nn   = n0 + n;
        const int srow = (e < 63) ? send_idx[nn*63 + e] : 0;   // e==63: dummy row
        const float* Rp = Rr + (size_t)((b*4 + k)*64 + nn)*128;
#pragma unroll
        for (int kc = 0; kc < 4; ++kc){
            int fg = kc*4 + fo;
            const float4* sv = (const float4*)(SfB + fg*512 + srow*8);
            const float4* rv = (const float4*)(Rp + fg*8);
            float4 s0 = sv[0], s1 = sv[1];
            float4 r0 = rv[0], r1 = rv[1];
            union { short8 v; unsigned int u[4]; } av;
            av.u[0] = pack_bf2(tanh2(s0.x+r0.x), tanh2(s0.y+r0.y));
            av.u[1] = pack_bf2(tanh2(s0.z+r0.z), tanh2(s0.w+r0.w));
            av.u[2] = pack_bf2(tanh2(s1.x+r1.x), tanh2(s1.y+r1.y));
            av.u[3] = pack_bf2(tanh2(s1.z+r1.z), tanh2(s1.w+r1.w));
            if (n == 0) a0[kc] = av.v; else a1[kc] = av.v;
        }
    }
    __syncthreads();   // w2s (async) + rel_s ready

    // ---- MFMA: each B-frag read feeds both receivers ----
    f32x4 acc0[8], acc1[8];
#pragma unroll
    for (int nt = 0; nt < 8; ++nt){ acc0[nt] = (f32x4)0.0f; acc1[nt] = (f32x4)0.0f; }

    const short8* w2v = (const short8*)w2s;
#pragma unroll
    for (int kc = 0; kc < 4; ++kc){
#pragma unroll
        for (int nt = 0; nt < 8; ++nt){
            short8 bf = w2v[(kc*8 + nt)*64 + lane];
            acc0[nt] = __builtin_amdgcn_mfma_f32_16x16x32_bf16(a0[kc], bf, acc0[nt], 0, 0, 0);
            acc1[nt] = __builtin_amdgcn_mfma_f32_16x16x32_bf16(a1[kc], bf, acc1[nt], 0, 0, 0);
        }
    }

    // ---- epilogue: tanh + rel weight; C/D row = wave*16 + (lane>>4)*4 + r ----
    const int re = wave*16 + ((lane >> 4) << 2);
    float b2v[8];
#pragma unroll
    for (int nt = 0; nt < 8; ++nt) b2v[nt] = b2x2[k*Hh + nt*16 + (lane & 15)];

#pragma unroll
    for (int n = 0; n < 2; ++n){
#pragma unroll
        for (int nt = 0; nt < 8; ++nt){
            f32x4 ac = (n == 0) ? acc0[nt] : acc1[nt];
            float s = 0.0f;
#pragma unroll
            for (int r = 0; r < 4; ++r)
                s = fmaf(rel_s[n][re + r], tanh2(fmaf(2.0f, ac[r], b2v[nt])), s);
            s += __shfl_xor(s, 16);
            s += __shfl_xor(s, 32);
            if (lane < 16) redu[wave][n][nt*16 + lane] = s;
        }
    }
    __syncthreads();
    {
        const int n = tid >> 7, h = tid & 127;
        float v = redu[0][n][h] + redu[1][n][h] + redu[2][n][h] + redu[3][n][h];
        aggp[(size_t)k*BNH + (size_t)(b*64 + n0 + n)*Hh + h] = v;
    }
}

// ---------------------------------------------------------------------------
// Kernel CA (fused GRU/MLP + next-step SR): 256 blocks x 256 thr, 4 nodes/blk.
//   threads <128: agg-sum, GRU, output MLP, pred write (as before)
//   all 256:      SR phase — 8 W1-GEMVs from LDS hnew, writes Sf (2x) and
//                 Rr (2x, +2*b1) for the NEXT step's kB.
// ---------------------------------------------------------------------------
__global__ void __launch_bounds__(256) kCA(const float* __restrict__ data,
                                           const float* __restrict__ aggp,
                                           float* __restrict__ hidden,
                                           float* __restrict__ prevpred,
                                           const float* __restrict__ Wr_in, const float* __restrict__ br_in,
                                           const float* __restrict__ Wi_in, const float* __restrict__ bi_in,
                                           const float* __restrict__ Wn_in, const float* __restrict__ bn_in,
                                           const float* __restrict__ Wr_h,  const float* __restrict__ Wi_h,
                                           const float* __restrict__ Wh_h,
                                           const float* __restrict__ Wo1,   const float* __restrict__ bo1,
                                           const float* __restrict__ Wo2,   const float* __restrict__ bo2,
                                           const float* __restrict__ Wo3,   const float* __restrict__ bo3,
                                           const float* __restrict__ W1,    const float* __restrict__ b1,
                                           float* __restrict__ Sf,          float* __restrict__ Rr,
                                           float* __restrict__ out, int t){
    __shared__ float aggL[4][Hh];
    __shared__ float hbuf[4][Hh];
    __shared__ float buf[4][Hh];
    __shared__ float insL[4][Dd];

    const int bn0 = blockIdx.x * 4;
    const int tid = threadIdx.x;
    const int h   = tid & 127;

#pragma unroll
    for (int s = tid; s < 512; s += 256){
        int g = s >> 7, hh2 = s & 127;
        int bn = bn0 + g;
        aggL[g][hh2] = (aggp[bn*Hh + hh2] + aggp[BNH + bn*Hh + hh2] +
                        aggp[2*BNH + bn*Hh + hh2] + aggp[3*BNH + bn*Hh + hh2]) * (1.0f/16.0f);
    }
    if (tid < 16){
        int g = tid >> 2, d = tid & 3;
        int bn = bn0 + g;
        insL[g][d] = (t < Tt) ? data[(bn*Dd + d)*Tt + t] : prevpred[bn*Dd + d];
    }
    __syncthreads();

    // ---- GRU (threads < 128) ----
    if (tid < 128){
        float rh[4] = {0,0,0,0}, ih[4] = {0,0,0,0}, hh[4] = {0,0,0,0};
        for (int f = 0; f < Hh; ++f){
            float wr = Wr_h[f*Hh + h], wi = Wi_h[f*Hh + h], wh = Wh_h[f*Hh + h];
#pragma unroll
            for (int g = 0; g < 4; ++g){
                float av = aggL[g][f];
                rh[g] += av*wr; ih[g] += av*wi; hh[g] += av*wh;
            }
        }
        const float wr0 = Wr_in[h],        wr1 = Wr_in[Hh + h],
                    wr2 = Wr_in[2*Hh + h], wr3 = Wr_in[3*Hh + h];
        const float wi0 = Wi_in[h],        wi1 = Wi_in[Hh + h],
                    wi2 = Wi_in[2*Hh + h], wi3 = Wi_in[3*Hh + h];
        const float wn0 = Wn_in[h],        wn1 = Wn_in[Hh + h],
                    wn2 = Wn_in[2*Hh + h], wn3 = Wn_in[3*Hh + h];
        const float brv = br_in[h], biv = bi_in[h], bnv = bn_in[h];
#pragma unroll
        for (int g = 0; g < 4; ++g){
            float i0 = insL[g][0], i1 = insL[g][1], i2 = insL[g][2], i3 = insL[g][3];
            float r  = sigmoid_fast(brv + i0*wr0 + i1*wr1 + i2*wr2 + i3*wr3 + rh[g]);
            float ii = sigmoid_fast(biv + i0*wi0 + i1*wi1 + i2*wi2 + i3*wi3 + ih[g]);
            float nn = tanh_fast   (bnv + i0*wn0 + i1*wn1 + i2*wn2 + i3*wn3 + r*hh[g]);
            float hold = hidden[(bn0+g)*Hh + h];
            float hnew = (1.0f - ii)*nn + ii*hold;
            hidden[(bn0+g)*Hh + h] = hnew;
            hbuf[g][h] = hnew;
            buf[g][h]  = hnew;
        }
    }
    __syncthreads();

    // ---- output MLP (threads < 128) ----
    float y1g[4];
    if (tid < 128){
        const float b1v = bo1[h];
#pragma unroll
        for (int g = 0; g < 4; ++g) y1g[g] = b1v;
        for (int f = 0; f < Hh; ++f){
            float wv = Wo1[f*Hh + h];
#pragma unroll
            for (int g = 0; g < 4; ++g) y1g[g] += buf[g][f]*wv;
        }
    }
    __syncthreads();
    if (tid < 128){
#pragma unroll
        for (int g = 0; g < 4; ++g) buf[g][h] = fmaxf(y1g[g], 0.0f);
    }
    __syncthreads();
    float y2g[4];
    if (tid < 128){
        const float b2v = bo2[h];
#pragma unroll
        for (int g = 0; g < 4; ++g) y2g[g] = b2v;
        for (int f = 0; f < Hh; ++f){
            float wv = Wo2[f*Hh + h];
#pragma unroll
            for (int g = 0; g < 4; ++g) y2g[g] += buf[g][f]*wv;
        }
    }
    __syncthreads();
    if (tid < 128){
#pragma unroll
        for (int g = 0; g < 4; ++g) buf[g][h] = fmaxf(y2g[g], 0.0f);
    }
    __syncthreads();

    if (tid < 16){
        int g = tid >> 2, d = tid & 3;
        float pv = bo3[d];
        for (int f = 0; f < Hh; ++f) pv += buf[g][f]*Wo3[f*Dd + d];
        pv += insL[g][d];
        int bn = bn0 + g;
        prevpred[bn*Dd + d] = pv;
        if (t >= Tt) out[(bn*Dd + d)*Ll + (t - Tt)] = pv;
    }

    // ---- SR phase for next step (all 256 threads) ----
    if (t < Tt + Ll - 1){
        const int th = tid & 127;
        const int kb = (tid >> 7) * 4;    // ksr base: 0..3 or 4..7
        float acc[4][4];
#pragma unroll
        for (int q = 0; q < 4; ++q)
#pragma unroll
            for (int g = 0; g < 4; ++g) acc[q][g] = 0.0f;

        const float* wp = W1 + (size_t)kb*Hh*Hh + th;
#pragma unroll 4
        for (int f = 0; f < Hh; ++f){
            float h0 = hbuf[0][f], h1 = hbuf[1][f], h2 = hbuf[2][f], h3 = hbuf[3][f];
#pragma unroll
            for (int q = 0; q < 4; ++q){
                float w = wp[(size_t)(q*Hh + f)*Hh];
                acc[q][0] += h0*w; acc[q][1] += h1*w;
                acc[q][2] += h2*w; acc[q][3] += h3*w;
            }
        }
        const int b   = bn0 >> 6;
        const int nd0 = bn0 & 63;
#pragma unroll
        for (int q = 0; q < 4; ++q){
            int ksr = kb + q, k = ksr >> 1;
            if ((ksr & 1) == 0){
                float* base = Sf + ((size_t)((b*4+k)*16 + (th>>3)))*512 + nd0*8 + (th&7);
#pragma unroll
                for (int g = 0; g < 4; ++g) base[g*8] = 2.0f*acc[q][g];
            } else {
                float bv = b1[k*Hh + th];
                float* base = Rr + ((size_t)((b*4+k)*64 + nd0))*128 + th;
#pragma unroll
                for (int g = 0; g < 4; ++g) base[g*128] = 2.0f*(acc[q][g] + bv);
            }
        }
    }
}

// ---------------------------------------------------------------------------
extern "C" void kernel_launch(void* const* d_in, const int* in_sizes, int n_in,
                              void* d_out, int out_size, void* d_ws, size_t ws_size,
                              hipStream_t stream){
    const float* data  = (const float*)d_in[0];
    const float* rel   = (const float*)d_in[1];
    const float* W1    = (const float*)d_in[2];
    const float* b1    = (const float*)d_in[3];
    const float* W2    = (const float*)d_in[4];
    const float* b2    = (const float*)d_in[5];
    const float* Wr_h  = (const float*)d_in[6];
    const float* Wi_h  = (const float*)d_in[7];
    const float* Wh_h  = (const float*)d_in[8];
    const float* Wr_in = (const float*)d_in[9];
    const float* br_in = (const float*)d_in[10];
    const float* Wi_in = (const float*)d_in[11];
    const float* bi_in = (const float*)d_in[12];
    const float* Wn_in = (const float*)d_in[13];
    const float* bn_in = (const float*)d_in[14];
    const float* Wo1   = (const float*)d_in[15];
    const float* bo1   = (const float*)d_in[16];
    const float* Wo2   = (const float*)d_in[17];
    const float* bo2   = (const float*)d_in[18];
    const float* Wo3   = (const float*)d_in[19];
    const float* bo3   = (const float*)d_in[20];
    const int* send_idx = (const int*)d_in[22];

    float* out = (float*)d_out;
    float* ws  = (float*)d_ws;

    // workspace (floats): hidden | prevpred | Sf | Rr | aggp[4] | W2f | b2x2
    float* hidden   = ws;                              // 131072
    float* prevpred = hidden + BNH;                    // 4096
    float* Sf       = prevpred + Bb*Nn*Dd;             // 524288
    float* Rr       = Sf + Bb*Kk*16*Nn*8;              // 524288
    float* aggp     = Rr + Bb*Kk*Nn*Hh;                // 524288
    unsigned short* W2f = (unsigned short*)(aggp + 4*BNH);  // 65536 ushort
    float* b2x2     = (float*)(W2f + 65536);           // 512

    hipMemsetAsync(hidden, 0, (Bb*Nn*Hh + Bb*Nn*Dd)*sizeof(float), stream);
    kW2f<<<33, 256, 0, stream>>>(W2, b2, W2f, b2x2);
    kInit<<<2048, 256, 0, stream>>>(b1, Sf, Rr);

    for (int t = 0; t < Tt + Ll; ++t){
        kB<<<2048, 256, 0, stream>>>(Sf, Rr, W2f, b2x2, rel, send_idx, aggp);
        kCA<<<256, 256, 0, stream>>>(data, aggp, hidden, prevpred,
                                     Wr_in, br_in, Wi_in, bi_in, Wn_in, bn_in,
                                     Wr_h, Wi_h, Wh_h,
                                     Wo1, bo1, Wo2, bo2, Wo3, bo3,
                                     W1, b1, Sf, Rr, out, t);
    }
}

// Round 7
// 2524.226 us; speedup vs baseline: 1.1507x; 1.1507x over previous
//
#include <hip/hip_runtime.h>
#include <hip/hip_bf16.h>
#include <math.h>

// Problem constants
#define Bb 16
#define Nn 64
#define Dd 4
#define Tt 40
#define Ll 10
#define Hh 128
#define Kk 4
#define Ee (Nn*(Nn-1))   // 4032
#define BNH (Bb*Nn*Hh)   // 131072

typedef __attribute__((ext_vector_type(8))) short short8;
typedef __attribute__((ext_vector_type(4))) float f32x4;

#define AS1 __attribute__((address_space(1)))
#define AS3 __attribute__((address_space(3)))

// tanh from PRE-DOUBLED argument: tanh2(2x) = tanh(x) = 1 - 2/(exp(2x)+1)
__device__ __forceinline__ float tanh2(float x2){
    float e = __expf(x2);
    float r = __builtin_amdgcn_rcpf(e + 1.0f);
    return fmaf(-2.0f, r, 1.0f);
}
__device__ __forceinline__ float tanh_fast(float x){
    return tanh2(2.0f * x);
}
__device__ __forceinline__ float sigmoid_fast(float x){
    return __builtin_amdgcn_rcpf(1.0f + __expf(-x));
}
__device__ __forceinline__ unsigned short f2bf(float x){   // RNE f32->bf16
    unsigned int u = __float_as_uint(x);
    return (unsigned short)((u + 0x7FFFu + ((u >> 16) & 1u)) >> 16);
}
// packed RNE f32x2 -> bf16x2 (v_cvt_pk_bf16_f32)
__device__ __forceinline__ unsigned int pack_bf2(float lo, float hi){
    union { __hip_bfloat162 h; unsigned int u; } cv;
    cv.h = __float22bfloat162_rn(make_float2(lo, hi));
    return cv.u;
}
// async global->LDS, 16B per lane
__device__ __forceinline__ void g2lds16(const void* g, void* l){
    __builtin_amdgcn_global_load_lds((const AS1 unsigned int*)g,
                                     (AS3 unsigned int*)l, 16, 0, 0);
}

// ---------------------------------------------------------------------------
// Precompute: W2 -> bf16 B-fragment layout (blocks 0..31); b2x2 = 2*b2 (blk 32)
// frag(k,kc,nt)[lane][i] = W2[k][kc*32+(lane>>4)*8+i][nt*16+(lane&15)]
// ---------------------------------------------------------------------------
__global__ void __launch_bounds__(256) kW2f(const float* __restrict__ W2,
                                            const float* __restrict__ b2,
                                            unsigned short* __restrict__ W2f,
                                            float* __restrict__ b2x2){
    if (blockIdx.x == 32){
        int i = threadIdx.x;
        b2x2[i]       = 2.0f * b2[i];
        b2x2[i + 256] = 2.0f * b2[i + 256];
        return;
    }
    int t    = blockIdx.x * 256 + threadIdx.x;   // 0..8191
    int lane = t & 63;
    int nt   = (t >> 6) & 7;
    int kc   = (t >> 9) & 3;
    int k    = (t >> 11) & 3;
    int col  = nt * 16 + (lane & 15);
    int fb   = kc * 32 + (lane >> 4) * 8;
    unsigned int w[4];
#pragma unroll
    for (int p = 0; p < 4; ++p){
        unsigned short lo = f2bf(W2[(k*Hh + fb + 2*p    )*Hh + col]);
        unsigned short hi = f2bf(W2[(k*Hh + fb + 2*p + 1)*Hh + col]);
        w[p] = (unsigned int)lo | ((unsigned int)hi << 16);
    }
    ((uint4*)W2f)[t] = make_uint4(w[0], w[1], w[2], w[3]);
}

// ---------------------------------------------------------------------------
// Precompute: W1 (fp32 [8][128][128], s = k*2+sr) -> bf16 B-fragment layout.
// frag(s,kc,nt)[lane][i] = W1[s*128 + kc*32+(lane>>4)*8+i][nt*16+(lane&15)]
// 64 blocks x 256 threads.
// ---------------------------------------------------------------------------
__global__ void __launch_bounds__(256) kW1f(const float* __restrict__ W1,
                                            unsigned short* __restrict__ W1f){
    int t    = blockIdx.x * 256 + threadIdx.x;   // 0..16383
    int lane = t & 63;
    int nt   = (t >> 6) & 7;
    int kc   = (t >> 9) & 3;
    int s    = t >> 11;                          // 0..7
    int col  = nt * 16 + (lane & 15);
    int fb   = kc * 32 + (lane >> 4) * 8;
    unsigned int w[4];
#pragma unroll
    for (int p = 0; p < 4; ++p){
        unsigned short lo = f2bf(W1[(size_t)(s*Hh + fb + 2*p    )*Hh + col]);
        unsigned short hi = f2bf(W1[(size_t)(s*Hh + fb + 2*p + 1)*Hh + col]);
        w[p] = (unsigned int)lo | ((unsigned int)hi << 16);
    }
    ((uint4*)W1f)[t] = make_uint4(w[0], w[1], w[2], w[3]);
}

// ---------------------------------------------------------------------------
// kInit: hidden==0 step-0 state: Sf = 0, Rr = 2*b1 broadcast.
// ---------------------------------------------------------------------------
__global__ void __launch_bounds__(256) kInit(const float* __restrict__ b1,
                                             float* __restrict__ Sf,
                                             float* __restrict__ Rr){
    int i = blockIdx.x*256 + threadIdx.x;   // 0..524287
    Sf[i] = 0.0f;
    Rr[i] = 2.0f * b1[((i >> 13) & 3)*Hh + (i & 127)];   // [b][k][node][h]
}

// ---------------------------------------------------------------------------
// Kernel A (MFMA SR): SR = hbf(bf16 A-frags) @ W1f(bf16 B-frags).
// Block = (b, s=k*2+sr, mh).  256 blocks x 256 thr, no LDS.
// Wave w: N-tiles {2w,2w+1}; M-tiles {mh*2, mh*2+1}.  16 MFMA/wave.
// Epilogue pre-doubles: Sf = 2*acc (frag-major), Rr = 2*(acc + b1).
// ---------------------------------------------------------------------------
__global__ void __launch_bounds__(256) kA(const unsigned short* __restrict__ hbf,
                                          const unsigned short* __restrict__ W1f,
                                          const float* __restrict__ b1,
                                          float* __restrict__ Sf,
                                          float* __restrict__ Rr){
    const int blk  = blockIdx.x;
    const int mh   = blk & 1;
    const int s    = (blk >> 1) & 7;
    const int b    = blk >> 4;
    const int tid  = threadIdx.x;
    const int wave = tid >> 6;
    const int lane = tid & 63;
    const int nt0  = wave * 2;
    const int k    = s >> 1, sr = s & 1;

    const short8* hv = (const short8*)hbf;   // [b][Mt][kc][lane]
    const short8* wv = (const short8*)W1f;   // [s][kc][nt][lane]

    short8 a[2][4], bf[2][4];
#pragma unroll
    for (int m = 0; m < 2; ++m)
#pragma unroll
        for (int kc = 0; kc < 4; ++kc)
            a[m][kc] = hv[((size_t)((b*4 + mh*2 + m)*4) + kc)*64 + lane];
#pragma unroll
    for (int n = 0; n < 2; ++n)
#pragma unroll
        for (int kc = 0; kc < 4; ++kc)
            bf[n][kc] = wv[((size_t)(s*4 + kc)*8 + nt0 + n)*64 + lane];

    f32x4 acc[2][2];
#pragma unroll
    for (int m = 0; m < 2; ++m){ acc[m][0] = (f32x4)0.0f; acc[m][1] = (f32x4)0.0f; }

#pragma unroll
    for (int kc = 0; kc < 4; ++kc)
#pragma unroll
        for (int m = 0; m < 2; ++m){
            acc[m][0] = __builtin_amdgcn_mfma_f32_16x16x32_bf16(a[m][kc], bf[0][kc], acc[m][0], 0, 0, 0);
            acc[m][1] = __builtin_amdgcn_mfma_f32_16x16x32_bf16(a[m][kc], bf[1][kc], acc[m][1], 0, 0, 0);
        }

    // C/D: col = lane&15, row = (lane>>4)*4 + r
    const int col = lane & 15;
    const int r0  = (lane >> 4) << 2;
#pragma unroll
    for (int n = 0; n < 2; ++n){
        const int h  = (nt0 + n)*16 + col;
        const float bv = (sr == 1) ? b1[k*Hh + h] : 0.0f;
#pragma unroll
        for (int m = 0; m < 2; ++m){
            const int Mt = mh*2 + m;
#pragma unroll
            for (int r = 0; r < 4; ++r){
                const int node = Mt*16 + r0 + r;
                const float v = 2.0f*(acc[m][n][r] + bv);
                if (sr == 0)
                    Sf[((size_t)((b*4+k)*16 + (h>>3)))*512 + node*8 + (h&7)] = v;
                else
                    Rr[((size_t)((b*4+k)*64 + node))*128 + h] = v;
            }
        }
    }
}

// ---------------------------------------------------------------------------
// Kernel B (MFMA, n-pair, B-frag register reuse): block = (b, npair, k).
// 2048 blocks, 256 threads.  Wave = edge-strip [16w,16w+16).
// ---------------------------------------------------------------------------
__global__ void __launch_bounds__(256) kB(const float* __restrict__ Sf,
                                          const float* __restrict__ Rr,
                                          const unsigned short* __restrict__ W2f,
                                          const float* __restrict__ b2x2,
                                          const float* __restrict__ rel,
                                          const int*   __restrict__ send_idx,
                                          float* __restrict__ aggp){
    __shared__ unsigned short w2s[32*512];   // 32KB
    __shared__ float rel_s[2][64];
    __shared__ float redu[4][2][Hh];         // 4KB

    const int blk  = blockIdx.x;
    const int k    = blk & 3;
    const int np   = (blk >> 2) & 31;
    const int b    = blk >> 7;
    const int n0   = np * 2;
    const int tid  = threadIdx.x;
    const int wave = tid >> 6;
    const int lane = tid & 63;

    // ---- async stage W2f k-slice ----
    {
        const uint4* src = (const uint4*)(W2f + (size_t)k*16384);
        uint4* dst = (uint4*)w2s;
#pragma unroll
        for (int i = 0; i < 8; ++i)
            g2lds16(src + tid + i*256, dst + tid + i*256);
    }
    if (tid < 63)                      rel_s[0][tid]     = rel[(b*Ee + n0*63 + tid)*Kk + k];
    else if (tid == 63)                rel_s[0][63]      = 0.0f;
    else if (tid >= 128 && tid < 191)  rel_s[1][tid-128] = rel[(b*Ee + (n0+1)*63 + (tid-128))*Kk + k];
    else if (tid == 191)               rel_s[1][63]      = 0.0f;

    // ---- build A-fragments for both receivers (registers only) ----
    const int e  = wave*16 + (lane & 15);
    const int fo = lane >> 4;
    const float* SfB = Sf + (size_t)((b*4 + k)*16)*512;
    short8 a0[4], a1[4];
#pragma unroll
    for (int n = 0; n < 2; ++n){
        const int nn   = n0 + n;
        const int srow = (e < 63) ? send_idx[nn*63 + e] : 0;   // e==63: dummy row
        const float* Rp = Rr + (size_t)((b*4 + k)*64 + nn)*128;
#pragma unroll
        for (int kc = 0; kc < 4; ++kc){
            int fg = kc*4 + fo;
            const float4* sv = (const float4*)(SfB + fg*512 + srow*8);
            const float4* rv = (const float4*)(Rp + fg*8);
            float4 s0 = sv[0], s1 = sv[1];
            float4 r0 = rv[0], r1 = rv[1];
            union { short8 v; unsigned int u[4]; } av;
            av.u[0] = pack_bf2(tanh2(s0.x+r0.x), tanh2(s0.y+r0.y));
            av.u[1] = pack_bf2(tanh2(s0.z+r0.z), tanh2(s0.w+r0.w));
            av.u[2] = pack_bf2(tanh2(s1.x+r1.x), tanh2(s1.y+r1.y));
            av.u[3] = pack_bf2(tanh2(s1.z+r1.z), tanh2(s1.w+r1.w));
            if (n == 0) a0[kc] = av.v; else a1[kc] = av.v;
        }
    }
    __syncthreads();   // w2s (async) + rel_s ready

    // ---- MFMA: each B-frag read feeds both receivers ----
    f32x4 acc0[8], acc1[8];
#pragma unroll
    for (int nt = 0; nt < 8; ++nt){ acc0[nt] = (f32x4)0.0f; acc1[nt] = (f32x4)0.0f; }

    const short8* w2v = (const short8*)w2s;
#pragma unroll
    for (int kc = 0; kc < 4; ++kc){
#pragma unroll
        for (int nt = 0; nt < 8; ++nt){
            short8 bfr = w2v[(kc*8 + nt)*64 + lane];
            acc0[nt] = __builtin_amdgcn_mfma_f32_16x16x32_bf16(a0[kc], bfr, acc0[nt], 0, 0, 0);
            acc1[nt] = __builtin_amdgcn_mfma_f32_16x16x32_bf16(a1[kc], bfr, acc1[nt], 0, 0, 0);
        }
    }

    // ---- epilogue: tanh + rel weight; C/D row = wave*16 + (lane>>4)*4 + r ----
    const int re = wave*16 + ((lane >> 4) << 2);
    float b2v[8];
#pragma unroll
    for (int nt = 0; nt < 8; ++nt) b2v[nt] = b2x2[k*Hh + nt*16 + (lane & 15)];

#pragma unroll
    for (int n = 0; n < 2; ++n){
#pragma unroll
        for (int nt = 0; nt < 8; ++nt){
            f32x4 ac = (n == 0) ? acc0[nt] : acc1[nt];
            float s = 0.0f;
#pragma unroll
            for (int r = 0; r < 4; ++r)
                s = fmaf(rel_s[n][re + r], tanh2(fmaf(2.0f, ac[r], b2v[nt])), s);
            s += __shfl_xor(s, 16);
            s += __shfl_xor(s, 32);
            if (lane < 16) redu[wave][n][nt*16 + lane] = s;
        }
    }
    __syncthreads();
    {
        const int n = tid >> 7, h = tid & 127;
        float v = redu[0][n][h] + redu[1][n][h] + redu[2][n][h] + redu[3][n][h];
        aggp[(size_t)k*BNH + (size_t)(b*64 + n0 + n)*Hh + h] = v;
    }
}

// ---------------------------------------------------------------------------
// Kernel C (4 nodes/block): agg sum, GRU, output MLP, pred; also emits hnew
// in bf16 A-fragment layout (hbf) for kA's MFMA.
// 256 blocks x 128 threads.
// ---------------------------------------------------------------------------
__global__ void __launch_bounds__(128) kC(const float* __restrict__ data,
                                          const float* __restrict__ aggp,
                                          float* __restrict__ hidden,
                                          float* __restrict__ prevpred,
                                          unsigned short* __restrict__ hbf,
                                          const float* __restrict__ Wr_in, const float* __restrict__ br_in,
                                          const float* __restrict__ Wi_in, const float* __restrict__ bi_in,
                                          const float* __restrict__ Wn_in, const float* __restrict__ bn_in,
                                          const float* __restrict__ Wr_h,  const float* __restrict__ Wi_h,
                                          const float* __restrict__ Wh_h,
                                          const float* __restrict__ Wo1,   const float* __restrict__ bo1,
                                          const float* __restrict__ Wo2,   const float* __restrict__ bo2,
                                          const float* __restrict__ Wo3,   const float* __restrict__ bo3,
                                          float* __restrict__ out, int t){
    __shared__ float aggL[4][Hh];
    __shared__ float buf[4][Hh];
    __shared__ float insL[4][Dd];

    const int bn0 = blockIdx.x * 4;
    const int h   = threadIdx.x;

#pragma unroll
    for (int g = 0; g < 4; ++g){
        int bn = bn0 + g;
        aggL[g][h] = (aggp[bn*Hh + h] + aggp[BNH + bn*Hh + h] +
                      aggp[2*BNH + bn*Hh + h] + aggp[3*BNH + bn*Hh + h]) * (1.0f/16.0f);
    }
    if (h < 16){
        int g = h >> 2, d = h & 3;
        int bn = bn0 + g;
        insL[g][d] = (t < Tt) ? data[(bn*Dd + d)*Tt + t] : prevpred[bn*Dd + d];
    }
    __syncthreads();

    // gate hidden-side GEMVs, 4 nodes per weight load
    float rh[4] = {0,0,0,0}, ih[4] = {0,0,0,0}, hh[4] = {0,0,0,0};
    for (int f = 0; f < Hh; ++f){
        float wr = Wr_h[f*Hh + h], wi = Wi_h[f*Hh + h], wh = Wh_h[f*Hh + h];
#pragma unroll
        for (int g = 0; g < 4; ++g){
            float av = aggL[g][f];
            rh[g] += av*wr; ih[g] += av*wi; hh[g] += av*wh;
        }
    }

    const float wr0 = Wr_in[h],        wr1 = Wr_in[Hh + h],
                wr2 = Wr_in[2*Hh + h], wr3 = Wr_in[3*Hh + h];
    const float wi0 = Wi_in[h],        wi1 = Wi_in[Hh + h],
                wi2 = Wi_in[2*Hh + h], wi3 = Wi_in[3*Hh + h];
    const float wn0 = Wn_in[h],        wn1 = Wn_in[Hh + h],
                wn2 = Wn_in[2*Hh + h], wn3 = Wn_in[3*Hh + h];
    const float brv = br_in[h], biv = bi_in[h], bnv = bn_in[h];

    // hbf address pieces for this h (node-dependent part added per g)
    const int kc  = h >> 5;
    const int lhi = (h >> 3) & 3;
    const int j   = h & 7;

#pragma unroll
    for (int g = 0; g < 4; ++g){
        float i0 = insL[g][0], i1 = insL[g][1], i2 = insL[g][2], i3 = insL[g][3];
        float r  = sigmoid_fast(brv + i0*wr0 + i1*wr1 + i2*wr2 + i3*wr3 + rh[g]);
        float ii = sigmoid_fast(biv + i0*wi0 + i1*wi1 + i2*wi2 + i3*wi3 + ih[g]);
        float nn = tanh_fast   (bnv + i0*wn0 + i1*wn1 + i2*wn2 + i3*wn3 + r*hh[g]);
        float hold = hidden[(bn0+g)*Hh + h];
        float hnew = (1.0f - ii)*nn + ii*hold;
        hidden[(bn0+g)*Hh + h] = hnew;
        buf[g][h] = hnew;
        // bf16 A-frag store: [b][Mt][kc][lane][j]
        int bn   = bn0 + g;
        int bb   = bn >> 6, node64 = bn & 63;
        int Mt   = node64 >> 4;
        int lane = (node64 & 15) + lhi*16;
        hbf[((size_t)((bb*4 + Mt)*4 + kc)*64 + lane)*8 + j] = f2bf(hnew);
    }
    __syncthreads();

    float y1[4]; const float b1v = bo1[h];
#pragma unroll
    for (int g = 0; g < 4; ++g) y1[g] = b1v;
    for (int f = 0; f < Hh; ++f){
        float wv = Wo1[f*Hh + h];
#pragma unroll
        for (int g = 0; g < 4; ++g) y1[g] += buf[g][f]*wv;
    }
    __syncthreads();
#pragma unroll
    for (int g = 0; g < 4; ++g) buf[g][h] = fmaxf(y1[g], 0.0f);
    __syncthreads();

    float y2[4]; const float b2v = bo2[h];
#pragma unroll
    for (int g = 0; g < 4; ++g) y2[g] = b2v;
    for (int f = 0; f < Hh; ++f){
        float wv = Wo2[f*Hh + h];
#pragma unroll
        for (int g = 0; g < 4; ++g) y2[g] += buf[g][f]*wv;
    }
    __syncthreads();
#pragma unroll
    for (int g = 0; g < 4; ++g) buf[g][h] = fmaxf(y2[g], 0.0f);
    __syncthreads();

    if (h < 16){
        int g = h >> 2, d = h & 3;
        float pv = bo3[d];
        for (int f = 0; f < Hh; ++f) pv += buf[g][f]*Wo3[f*Dd + d];
        pv += insL[g][d];
        int bn = bn0 + g;
        prevpred[bn*Dd + d] = pv;
        if (t >= Tt) out[(bn*Dd + d)*Ll + (t - Tt)] = pv;
    }
}

// ---------------------------------------------------------------------------
extern "C" void kernel_launch(void* const* d_in, const int* in_sizes, int n_in,
                              void* d_out, int out_size, void* d_ws, size_t ws_size,
                              hipStream_t stream){
    const float* data  = (const float*)d_in[0];
    const float* rel   = (const float*)d_in[1];
    const float* W1    = (const float*)d_in[2];
    const float* b1    = (const float*)d_in[3];
    const float* W2    = (const float*)d_in[4];
    const float* b2    = (const float*)d_in[5];
    const float* Wr_h  = (const float*)d_in[6];
    const float* Wi_h  = (const float*)d_in[7];
    const float* Wh_h  = (const float*)d_in[8];
    const float* Wr_in = (const float*)d_in[9];
    const float* br_in = (const float*)d_in[10];
    const float* Wi_in = (const float*)d_in[11];
    const float* bi_in = (const float*)d_in[12];
    const float* Wn_in = (const float*)d_in[13];
    const float* bn_in = (const float*)d_in[14];
    const float* Wo1   = (const float*)d_in[15];
    const float* bo1   = (const float*)d_in[16];
    const float* Wo2   = (const float*)d_in[17];
    const float* bo2   = (const float*)d_in[18];
    const float* Wo3   = (const float*)d_in[19];
    const float* bo3   = (const float*)d_in[20];
    const int* send_idx = (const int*)d_in[22];

    float* out = (float*)d_out;
    float* ws  = (float*)d_ws;

    // workspace (floats): hidden | prevpred | Sf | Rr | aggp[4] | W2f | b2x2 | W1f | hbf
    float* hidden   = ws;                              // 131072
    float* prevpred = hidden + BNH;                    // 4096
    float* Sf       = prevpred + Bb*Nn*Dd;             // 524288
    float* Rr       = Sf + Bb*Kk*16*Nn*8;              // 524288
    float* aggp     = Rr + Bb*Kk*Nn*Hh;                // 524288
    unsigned short* W2f = (unsigned short*)(aggp + 4*BNH);   // 65536 ushort
    float* b2x2     = (float*)(W2f + 65536);           // 512
    unsigned short* W1f = (unsigned short*)(b2x2 + 512);     // 131072 ushort
    unsigned short* hbf = W1f + 131072;                // 131072 ushort

    hipMemsetAsync(hidden, 0, (Bb*Nn*Hh + Bb*Nn*Dd)*sizeof(float), stream);
    kW2f<<<33, 256, 0, stream>>>(W2, b2, W2f, b2x2);
    kW1f<<<64, 256, 0, stream>>>(W1, W1f);
    kInit<<<2048, 256, 0, stream>>>(b1, Sf, Rr);

    for (int t = 0; t < Tt + Ll; ++t){
        kB<<<2048, 256, 0, stream>>>(Sf, Rr, W2f, b2x2, rel, send_idx, aggp);
        kC<<<256, 128, 0, stream>>>(data, aggp, hidden, prevpred, hbf,
                                    Wr_in, br_in, Wi_in, bi_in, Wn_in, bn_in,
                                    Wr_h, Wi_h, Wh_h,
                                    Wo1, bo1, Wo2, bo2, Wo3, bo3, out, t);
        if (t < Tt + Ll - 1)
            kA<<<256, 256, 0, stream>>>(hbf, W1f, b1, Sf, Rr);
    }
}

// Round 9
// 2360.351 us; speedup vs baseline: 1.2306x; 1.0694x over previous
//
#include <hip/hip_runtime.h>
#include <hip/hip_bf16.h>
#include <math.h>

// Problem constants
#define Bb 16
#define Nn 64
#define Dd 4
#define Tt 40
#define Ll 10
#define Hh 128
#define Kk 4
#define Ee (Nn*(Nn-1))   // 4032
#define BNH (Bb*Nn*Hh)   // 131072
#define SIGMA 2.8853900817779268f   // 2*log2(e): tanh(x)=1-2/(exp2(SIGMA*x)+1)

typedef __attribute__((ext_vector_type(8))) short short8;
typedef __attribute__((ext_vector_type(4))) float f32x4;

#define AS1 __attribute__((address_space(1)))
#define AS3 __attribute__((address_space(3)))

// tanh from PRE-SCALED argument y = SIGMA*x:  tanh(x) = 1 - 2/(exp2(y)+1)
__device__ __forceinline__ float tanhE(float y){
    float e = __builtin_amdgcn_exp2f(y);
    float r = __builtin_amdgcn_rcpf(e + 1.0f);
    return fmaf(-2.0f, r, 1.0f);
}
__device__ __forceinline__ float tanh_fast(float x){ return tanhE(SIGMA * x); }
__device__ __forceinline__ float sigmoid_fast(float x){
    return __builtin_amdgcn_rcpf(1.0f + __expf(-x));
}
__device__ __forceinline__ unsigned short f2bf(float x){   // RNE f32->bf16
    unsigned int u = __float_as_uint(x);
    return (unsigned short)((u + 0x7FFFu + ((u >> 16) & 1u)) >> 16);
}
// packed RNE f32x2 -> bf16x2 (v_cvt_pk_bf16_f32)
__device__ __forceinline__ unsigned int pack_bf2(float lo, float hi){
    union { __hip_bfloat162 h; unsigned int u; } cv;
    cv.h = __float22bfloat162_rn(make_float2(lo, hi));
    return cv.u;
}
// async global->LDS, 16B per lane
__device__ __forceinline__ void g2lds16(const void* g, void* l){
    __builtin_amdgcn_global_load_lds((const AS1 unsigned int*)g,
                                     (AS3 unsigned int*)l, 16, 0, 0);
}

// ---------------------------------------------------------------------------
// Precompute: W2 -> bf16 B-frag layout (blocks 0..31); b2l = SIGMA*b2 (blk 32)
// frag(k,kc,nt)[lane][i] = W2[k][kc*32+(lane>>4)*8+i][nt*16+(lane&15)]
// ---------------------------------------------------------------------------
__global__ void __launch_bounds__(256) kW2f(const float* __restrict__ W2,
                                            const float* __restrict__ b2,
                                            unsigned short* __restrict__ W2f,
                                            float* __restrict__ b2l){
    if (blockIdx.x == 32){
        int i = threadIdx.x;
        b2l[i]       = SIGMA * b2[i];
        b2l[i + 256] = SIGMA * b2[i + 256];
        return;
    }
    int t    = blockIdx.x * 256 + threadIdx.x;   // 0..8191
    int lane = t & 63;
    int nt   = (t >> 6) & 7;
    int kc   = (t >> 9) & 3;
    int k    = (t >> 11) & 3;
    int col  = nt * 16 + (lane & 15);
    int fb   = kc * 32 + (lane >> 4) * 8;
    unsigned int w[4];
#pragma unroll
    for (int p = 0; p < 4; ++p){
        unsigned short lo = f2bf(W2[(k*Hh + fb + 2*p    )*Hh + col]);
        unsigned short hi = f2bf(W2[(k*Hh + fb + 2*p + 1)*Hh + col]);
        w[p] = (unsigned int)lo | ((unsigned int)hi << 16);
    }
    ((uint4*)W2f)[t] = make_uint4(w[0], w[1], w[2], w[3]);
}

// ---------------------------------------------------------------------------
// Precompute: W1 -> bf16 B-frag layout.  64 blocks x 256 threads.
// ---------------------------------------------------------------------------
__global__ void __launch_bounds__(256) kW1f(const float* __restrict__ W1,
                                            unsigned short* __restrict__ W1f){
    int t    = blockIdx.x * 256 + threadIdx.x;   // 0..16383
    int lane = t & 63;
    int nt   = (t >> 6) & 7;
    int kc   = (t >> 9) & 3;
    int s    = t >> 11;                          // 0..7
    int col  = nt * 16 + (lane & 15);
    int fb   = kc * 32 + (lane >> 4) * 8;
    unsigned int w[4];
#pragma unroll
    for (int p = 0; p < 4; ++p){
        unsigned short lo = f2bf(W1[(size_t)(s*Hh + fb + 2*p    )*Hh + col]);
        unsigned short hi = f2bf(W1[(size_t)(s*Hh + fb + 2*p + 1)*Hh + col]);
        w[p] = (unsigned int)lo | ((unsigned int)hi << 16);
    }
    ((uint4*)W1f)[t] = make_uint4(w[0], w[1], w[2], w[3]);
}

// ---------------------------------------------------------------------------
// kInit: step-0 state (hidden = 0): Sf = 0, Rr = SIGMA*b1 broadcast.  fp32.
// ---------------------------------------------------------------------------
__global__ void __launch_bounds__(256) kInit(const float* __restrict__ b1,
                                             float* __restrict__ Sf,
                                             float* __restrict__ Rr){
    int i = blockIdx.x*256 + threadIdx.x;   // 0..524287
    Sf[i] = 0.0f;
    Rr[i] = SIGMA * b1[((i >> 13) & 3)*Hh + (i & 127)];   // [b][k][node][h]
}

// ---------------------------------------------------------------------------
// Kernel A (MFMA SR): SR = hbf @ W1f.  blk = inner*64 + (4b+k), inner=sr*2+mh
// -> XCD(blk%8) == (4b+k)%8 matches kB's readers of (b,k).
// fp32 outputs, pre-scaled by SIGMA: Sf (frag-major), Rr (+b1, row-major).
// ---------------------------------------------------------------------------
__global__ void __launch_bounds__(256) kA(const unsigned short* __restrict__ hbf,
                                          const unsigned short* __restrict__ W1f,
                                          const float* __restrict__ b1,
                                          float* __restrict__ Sf,
                                          float* __restrict__ Rr){
    const int blk   = blockIdx.x;
    const int bk    = blk & 63;
    const int b     = bk >> 2;
    const int k     = bk & 3;
    const int inner = blk >> 6;
    const int sr    = inner >> 1;
    const int mh    = inner & 1;
    const int s     = k*2 + sr;
    const int tid  = threadIdx.x;
    const int wave = tid >> 6;
    const int lane = tid & 63;
    const int nt0  = wave * 2;

    const short8* hv = (const short8*)hbf;   // [b][Mt][kc][lane]
    const short8* wv = (const short8*)W1f;   // [s][kc][nt][lane]

    short8 a[2][4], bf[2][4];
#pragma unroll
    for (int m = 0; m < 2; ++m)
#pragma unroll
        for (int kc = 0; kc < 4; ++kc)
            a[m][kc] = hv[((size_t)((b*4 + mh*2 + m)*4) + kc)*64 + lane];
#pragma unroll
    for (int n = 0; n < 2; ++n)
#pragma unroll
        for (int kc = 0; kc < 4; ++kc)
            bf[n][kc] = wv[((size_t)(s*4 + kc)*8 + nt0 + n)*64 + lane];

    f32x4 acc[2][2];
#pragma unroll
    for (int m = 0; m < 2; ++m){ acc[m][0] = (f32x4)0.0f; acc[m][1] = (f32x4)0.0f; }

#pragma unroll
    for (int kc = 0; kc < 4; ++kc)
#pragma unroll
        for (int m = 0; m < 2; ++m){
            acc[m][0] = __builtin_amdgcn_mfma_f32_16x16x32_bf16(a[m][kc], bf[0][kc], acc[m][0], 0, 0, 0);
            acc[m][1] = __builtin_amdgcn_mfma_f32_16x16x32_bf16(a[m][kc], bf[1][kc], acc[m][1], 0, 0, 0);
        }

    // C/D: col = lane&15, row = (lane>>4)*4 + r
    const int col = lane & 15;
    const int r0  = (lane >> 4) << 2;
#pragma unroll
    for (int n = 0; n < 2; ++n){
        const int h  = (nt0 + n)*16 + col;
        const float bv = (sr == 1) ? b1[k*Hh + h] : 0.0f;
#pragma unroll
        for (int m = 0; m < 2; ++m){
            const int Mt = mh*2 + m;
#pragma unroll
            for (int r = 0; r < 4; ++r){
                const int node = Mt*16 + r0 + r;
                const float v = SIGMA*(acc[m][n][r] + bv);
                if (sr == 0)
                    Sf[((size_t)((b*4+k)*16 + (h>>3)))*512 + node*8 + (h&7)] = v;
                else
                    Rr[((size_t)((b*4+k)*64 + node))*128 + h] = v;
            }
        }
    }
}

// ---------------------------------------------------------------------------
// Kernel B (MFMA, n-quad, 2 phases): blk = nq*64 + (4b+k), 1024 blocks.
// Wave = edge-strip [16w,16w+16).  Per phase (2 receivers):
//   fp32 Sf/Rr loads (pre-scaled) -> tanhE -> A-frags; MFMA with B-frag reuse;
//   epilogue tanhE + rel weight -> redu.  Single cross-wave reduce at end.
// ---------------------------------------------------------------------------
__global__ void __launch_bounds__(256) kB(const float* __restrict__ Sf,
                                          const float* __restrict__ Rr,
                                          const unsigned short* __restrict__ W2f,
                                          const float* __restrict__ b2l,
                                          const float* __restrict__ rel,
                                          const int*   __restrict__ send_idx,
                                          float* __restrict__ aggp){
    __shared__ unsigned short w2s[32*512];   // 32KB
    __shared__ float rel_s[4][64];           // 1KB
    __shared__ float b2s[Hh];                // 0.5KB
    __shared__ float redu[4][4][Hh];         // 8KB

    const int blk  = blockIdx.x;
    const int bk   = blk & 63;
    const int nq   = blk >> 6;
    const int b    = bk >> 2;
    const int k    = bk & 3;
    const int n0   = nq * 4;
    const int tid  = threadIdx.x;
    const int wave = tid >> 6;
    const int lane = tid & 63;

    // ---- async stage W2f k-slice ----
    {
        const uint4* src = (const uint4*)(W2f + (size_t)k*16384);
        uint4* dst = (uint4*)w2s;
#pragma unroll
        for (int i = 0; i < 8; ++i)
            g2lds16(src + tid + i*256, dst + tid + i*256);
    }
    {   // rel for 4 receivers (e=63 dummy -> 0)
        int g = tid >> 6, e = tid & 63;
        rel_s[g][e] = (e < 63) ? rel[(b*Ee + (n0+g)*63 + e)*Kk + k] : 0.0f;
    }
    if (tid < 128) b2s[tid] = b2l[k*Hh + tid];
    __syncthreads();   // w2s (vmcnt drained) + rel_s/b2s ready

    const int e  = wave*16 + (lane & 15);
    const int fo = lane >> 4;
    const float* SfB = Sf + (size_t)((b*4 + k)*16)*512;

    const int re   = wave*16 + ((lane >> 4) << 2);
    const int colb = lane & 15;
    const short8* w2v = (const short8*)w2s;

#pragma unroll
    for (int ph = 0; ph < 2; ++ph){
        // ---- build A-frags for this phase's 2 receivers ----
        short8 a0[4], a1[4];
#pragma unroll
        for (int n = 0; n < 2; ++n){
            const int nn = n0 + ph*2 + n;
            int srow = 0; if (e < 63) srow = send_idx[nn*63 + e];
            const float* Rp = Rr + (size_t)((b*4 + k)*64 + nn)*128;
#pragma unroll
            for (int kc = 0; kc < 4; ++kc){
                const int fg = kc*4 + fo;
                const float4* sv = (const float4*)(SfB + fg*512 + srow*8);
                const float4* rv = (const float4*)(Rp + fg*8);
                float4 s0 = sv[0], s1 = sv[1];
                float4 r0 = rv[0], r1 = rv[1];
                union { short8 v; unsigned int u[4]; } av;
                av.u[0] = pack_bf2(tanhE(s0.x+r0.x), tanhE(s0.y+r0.y));
                av.u[1] = pack_bf2(tanhE(s0.z+r0.z), tanhE(s0.w+r0.w));
                av.u[2] = pack_bf2(tanhE(s1.x+r1.x), tanhE(s1.y+r1.y));
                av.u[3] = pack_bf2(tanhE(s1.z+r1.z), tanhE(s1.w+r1.w));
                if (n == 0) a0[kc] = av.v; else a1[kc] = av.v;
            }
        }

        // ---- MFMA: B-frag read feeds both receivers ----
        f32x4 acc0[8], acc1[8];
#pragma unroll
        for (int nt = 0; nt < 8; ++nt){ acc0[nt] = (f32x4)0.0f; acc1[nt] = (f32x4)0.0f; }
#pragma unroll
        for (int kc = 0; kc < 4; ++kc){
#pragma unroll
            for (int nt = 0; nt < 8; ++nt){
                short8 bfr = w2v[(kc*8 + nt)*64 + lane];
                acc0[nt] = __builtin_amdgcn_mfma_f32_16x16x32_bf16(a0[kc], bfr, acc0[nt], 0, 0, 0);
                acc1[nt] = __builtin_amdgcn_mfma_f32_16x16x32_bf16(a1[kc], bfr, acc1[nt], 0, 0, 0);
            }
        }

        // ---- epilogue: tanhE + rel weight, shfl reduce, stash in redu ----
#pragma unroll
        for (int n = 0; n < 2; ++n){
            const float* relp = rel_s[ph*2 + n];
#pragma unroll
            for (int nt = 0; nt < 8; ++nt){
                f32x4 ac = (n == 0) ? acc0[nt] : acc1[nt];
                float bv = b2s[nt*16 + colb];
                float s = 0.0f;
#pragma unroll
                for (int r = 0; r < 4; ++r)
                    s = fmaf(relp[re + r], tanhE(fmaf(SIGMA, ac[r], bv)), s);
                s += __shfl_xor(s, 16);
                s += __shfl_xor(s, 32);
                if (lane < 16) redu[wave][ph*2 + n][nt*16 + lane] = s;
            }
        }
    }

    __syncthreads();
#pragma unroll
    for (int i = 0; i < 2; ++i){
        int idx = tid + i*256;
        int rcv = idx >> 7, h = idx & 127;
        float v = redu[0][rcv][h] + redu[1][rcv][h] + redu[2][rcv][h] + redu[3][rcv][h];
        aggp[(size_t)k*BNH + (size_t)(b*64 + n0 + rcv)*Hh + h] = v;
    }
}

// ---------------------------------------------------------------------------
// Kernel C (4 nodes/block): agg sum, GRU, output MLP, pred; emits hnew in
// bf16 A-frag layout (hbf) for kA.  256 blocks x 128 threads.
// ---------------------------------------------------------------------------
__global__ void __launch_bounds__(128) kC(const float* __restrict__ data,
                                          const float* __restrict__ aggp,
                                          float* __restrict__ hidden,
                                          float* __restrict__ prevpred,
                                          unsigned short* __restrict__ hbf,
                                          const float* __restrict__ Wr_in, const float* __restrict__ br_in,
                                          const float* __restrict__ Wi_in, const float* __restrict__ bi_in,
                                          const float* __restrict__ Wn_in, const float* __restrict__ bn_in,
                                          const float* __restrict__ Wr_h,  const float* __restrict__ Wi_h,
                                          const float* __restrict__ Wh_h,
                                          const float* __restrict__ Wo1,   const float* __restrict__ bo1,
                                          const float* __restrict__ Wo2,   const float* __restrict__ bo2,
                                          const float* __restrict__ Wo3,   const float* __restrict__ bo3,
                                          float* __restrict__ out, int t){
    __shared__ float aggL[4][Hh];
    __shared__ float buf[4][Hh];
    __shared__ float insL[4][Dd];

    const int bn0 = blockIdx.x * 4;
    const int h   = threadIdx.x;

#pragma unroll
    for (int g = 0; g < 4; ++g){
        int bn = bn0 + g;
        aggL[g][h] = (aggp[bn*Hh + h] + aggp[BNH + bn*Hh + h] +
                      aggp[2*BNH + bn*Hh + h] + aggp[3*BNH + bn*Hh + h]) * (1.0f/16.0f);
    }
    if (h < 16){
        int g = h >> 2, d = h & 3;
        int bn = bn0 + g;
        insL[g][d] = (t < Tt) ? data[(bn*Dd + d)*Tt + t] : prevpred[bn*Dd + d];
    }
    __syncthreads();

    float rh[4] = {0,0,0,0}, ih[4] = {0,0,0,0}, hh[4] = {0,0,0,0};
    for (int f = 0; f < Hh; ++f){
        float wr = Wr_h[f*Hh + h], wi = Wi_h[f*Hh + h], wh = Wh_h[f*Hh + h];
#pragma unroll
        for (int g = 0; g < 4; ++g){
            float av = aggL[g][f];
            rh[g] += av*wr; ih[g] += av*wi; hh[g] += av*wh;
        }
    }

    const float wr0 = Wr_in[h],        wr1 = Wr_in[Hh + h],
                wr2 = Wr_in[2*Hh + h], wr3 = Wr_in[3*Hh + h];
    const float wi0 = Wi_in[h],        wi1 = Wi_in[Hh + h],
                wi2 = Wi_in[2*Hh + h], wi3 = Wi_in[3*Hh + h];
    const float wn0 = Wn_in[h],        wn1 = Wn_in[Hh + h],
                wn2 = Wn_in[2*Hh + h], wn3 = Wn_in[3*Hh + h];
    const float brv = br_in[h], biv = bi_in[h], bnv = bn_in[h];

    const int kc  = h >> 5;
    const int lhi = (h >> 3) & 3;
    const int j   = h & 7;

#pragma unroll
    for (int g = 0; g < 4; ++g){
        float i0 = insL[g][0], i1 = insL[g][1], i2 = insL[g][2], i3 = insL[g][3];
        float r  = sigmoid_fast(brv + i0*wr0 + i1*wr1 + i2*wr2 + i3*wr3 + rh[g]);
        float ii = sigmoid_fast(biv + i0*wi0 + i1*wi1 + i2*wi2 + i3*wi3 + ih[g]);
        float nn = tanh_fast   (bnv + i0*wn0 + i1*wn1 + i2*wn2 + i3*wn3 + r*hh[g]);
        float hold = hidden[(bn0+g)*Hh + h];
        float hnew = (1.0f - ii)*nn + ii*hold;
        hidden[(bn0+g)*Hh + h] = hnew;
        buf[g][h] = hnew;
        int bn   = bn0 + g;
        int bb   = bn >> 6, node64 = bn & 63;
        int Mt   = node64 >> 4;
        int lane = (node64 & 15) + lhi*16;
        hbf[((size_t)((bb*4 + Mt)*4 + kc)*64 + lane)*8 + j] = f2bf(hnew);
    }
    __syncthreads();

    float y1[4]; const float b1v = bo1[h];
#pragma unroll
    for (int g = 0; g < 4; ++g) y1[g] = b1v;
    for (int f = 0; f < Hh; ++f){
        float wv = Wo1[f*Hh + h];
#pragma unroll
        for (int g = 0; g < 4; ++g) y1[g] += buf[g][f]*wv;
    }
    __syncthreads();
#pragma unroll
    for (int g = 0; g < 4; ++g) buf[g][h] = fmaxf(y1[g], 0.0f);
    __syncthreads();

    float y2[4]; const float b2v = bo2[h];
#pragma unroll
    for (int g = 0; g < 4; ++g) y2[g] = b2v;
    for (int f = 0; f < Hh; ++f){
        float wv = Wo2[f*Hh + h];
#pragma unroll
        for (int g = 0; g < 4; ++g) y2[g] += buf[g][f]*wv;
    }
    __syncthreads();
#pragma unroll
    for (int g = 0; g < 4; ++g) buf[g][h] = fmaxf(y2[g], 0.0f);
    __syncthreads();

    if (h < 16){
        int g = h >> 2, d = h & 3;
        float pv = bo3[d];
        for (int f = 0; f < Hh; ++f) pv += buf[g][f]*Wo3[f*Dd + d];
        pv += insL[g][d];
        int bn = bn0 + g;
        prevpred[bn*Dd + d] = pv;
        if (t >= Tt) out[(bn*Dd + d)*Ll + (t - Tt)] = pv;
    }
}

// ---------------------------------------------------------------------------
extern "C" void kernel_launch(void* const* d_in, const int* in_sizes, int n_in,
                              void* d_out, int out_size, void* d_ws, size_t ws_size,
                              hipStream_t stream){
    const float* data  = (const float*)d_in[0];
    const float* rel   = (const float*)d_in[1];
    const float* W1    = (const float*)d_in[2];
    const float* b1    = (const float*)d_in[3];
    const float* W2    = (const float*)d_in[4];
    const float* b2    = (const float*)d_in[5];
    const float* Wr_h  = (const float*)d_in[6];
    const float* Wi_h  = (const float*)d_in[7];
    const float* Wh_h  = (const float*)d_in[8];
    const float* Wr_in = (const float*)d_in[9];
    const float* br_in = (const float*)d_in[10];
    const float* Wi_in = (const float*)d_in[11];
    const float* bi_in = (const float*)d_in[12];
    const float* Wn_in = (const float*)d_in[13];
    const float* bn_in = (const float*)d_in[14];
    const float* Wo1   = (const float*)d_in[15];
    const float* bo1   = (const float*)d_in[16];
    const float* Wo2   = (const float*)d_in[17];
    const float* bo2   = (const float*)d_in[18];
    const float* Wo3   = (const float*)d_in[19];
    const float* bo3   = (const float*)d_in[20];
    const int* send_idx = (const int*)d_in[22];

    float* out = (float*)d_out;
    float* ws  = (float*)d_ws;

    // workspace (floats): hidden | prevpred | Sf | Rr | aggp[4] | W2f | b2l | W1f | hbf
    float* hidden   = ws;                              // 131072
    float* prevpred = hidden + BNH;                    // 4096
    float* Sf       = prevpred + Bb*Nn*Dd;             // 524288
    float* Rr       = Sf + Bb*Kk*16*Nn*8;              // 524288
    float* aggp     = Rr + Bb*Kk*Nn*Hh;                // 4*131072
    unsigned short* W2f = (unsigned short*)(aggp + 4*BNH);   // 65536 us
    float* b2l      = (float*)(W2f + 65536);           // 512
    unsigned short* W1f = (unsigned short*)(b2l + 512);      // 131072 us
    unsigned short* hbf = W1f + 131072;                // 131072 us

    hipMemsetAsync(hidden, 0, (Bb*Nn*Hh + Bb*Nn*Dd)*sizeof(float), stream);
    kW2f<<<33, 256, 0, stream>>>(W2, b2, W2f, b2l);
    kW1f<<<64, 256, 0, stream>>>(W1, W1f);
    kInit<<<2048, 256, 0, stream>>>(b1, Sf, Rr);

    for (int t = 0; t < Tt + Ll; ++t){
        kB<<<1024, 256, 0, stream>>>(Sf, Rr, W2f, b2l, rel, send_idx, aggp);
        kC<<<256, 128, 0, stream>>>(data, aggp, hidden, prevpred, hbf,
                                    Wr_in, br_in, Wi_in, bi_in, Wn_in, bn_in,
                                    Wr_h, Wi_h, Wh_h,
                                    Wo1, bo1, Wo2, bo2, Wo3, bo3, out, t);
        if (t < Tt + Ll - 1)
            kA<<<256, 256, 0, stream>>>(hbf, W1f, b1, Sf, Rr);
    }
}